// Round 6
// baseline (867.110 us; speedup 1.0000x reference)
//
#include <hip/hip_runtime.h>

#define NN 4681        // total nodes
#define NI 585         // internal (parent) nodes
#define GRID 512

__device__ __forceinline__ float sigm(float x) { return 1.f / (1.f + expf(-x)); }

struct Smem {
  union {
    struct { float As[16][132]; float Bs[16][68]; int toks[128]; } g;
    struct { float hs[300]; float siou[900]; float sc[300]; float sh[300]; } n;
  };
};

// Device-scope grid barrier: all GRID blocks co-resident by construction.
__device__ __forceinline__ void gsync(unsigned* bar, int k) {
  __syncthreads();
  if (threadIdx.x == 0) {
    __threadfence();                       // release: flush this block's writes
    atomicAdd(&bar[k], 1u);
    int tries = 0;
    while (atomicAdd(&bar[k], 0u) < (unsigned)GRID) {
      __builtin_amdgcn_s_sleep(8);
      if (++tries > 2000000) break;        // escape hatch: fail loud, never hang
    }
    __threadfence();                       // acquire: invalidate stale cache
  }
  __syncthreads();
}

// ---- X GEMM tile: C[row0..+127][col0..+63] of gather(embed,tokens)@[W_ioux|W_fx] ----
__device__ void gemm_x_tile(Smem& sm, int row0, int col0,
    const int* __restrict__ tokens, const float* __restrict__ embed,
    const float* __restrict__ W_ioux, const float* __restrict__ W_fx,
    const float* __restrict__ b_ioux, const float* __restrict__ b_fx,
    float* __restrict__ xiou, float* __restrict__ fxo)
{
  const int tid = threadIdx.x;
  __syncthreads();                          // protect toks/As/Bs from previous use
  if (tid < 128) {
    int r = row0 + tid;
    sm.g.toks[tid] = (r < NN) ? tokens[r] : 0;
  }
  float acc[8][4] = {};
  const int trow = (tid >> 4) * 8;
  const int tcol = (tid & 15) * 4;
  const int ar  = tid >> 1;
  const int akh = (tid & 1) * 8;
  const int bk  = tid >> 4;
  const int bc  = (tid & 15) * 4;
  for (int k0 = 0; k0 < 300; k0 += 16) {
    __syncthreads();
    {
      float4 v0 = {0,0,0,0}, v1 = {0,0,0,0};
      const int kb = k0 + akh;
      const float* src = embed + (size_t)sm.g.toks[ar] * 300;
      if (kb + 3 < 300) v0 = *(const float4*)(src + kb);
      if (kb + 7 < 300) v1 = *(const float4*)(src + kb + 4);
      sm.g.As[akh+0][ar] = v0.x; sm.g.As[akh+1][ar] = v0.y; sm.g.As[akh+2][ar] = v0.z; sm.g.As[akh+3][ar] = v0.w;
      sm.g.As[akh+4][ar] = v1.x; sm.g.As[akh+5][ar] = v1.y; sm.g.As[akh+6][ar] = v1.z; sm.g.As[akh+7][ar] = v1.w;
    }
    {
      float4 v = {0,0,0,0};
      const int k = k0 + bk;
      const int col = col0 + bc;
      if (k < 300) {
        if (col < 900)        v = *(const float4*)(W_ioux + (size_t)k * 900 + col);
        else if (col < 1200)  v = *(const float4*)(W_fx + (size_t)k * 300 + (col - 900));
      }
      *(float4*)&sm.g.Bs[bk][bc] = v;
    }
    __syncthreads();
#pragma unroll
    for (int kk = 0; kk < 16; ++kk) {
      float4 a0 = *(const float4*)&sm.g.As[kk][trow];
      float4 a1 = *(const float4*)&sm.g.As[kk][trow + 4];
      float4 b  = *(const float4*)&sm.g.Bs[kk][tcol];
      float av[8] = {a0.x,a0.y,a0.z,a0.w,a1.x,a1.y,a1.z,a1.w};
      float bv[4] = {b.x,b.y,b.z,b.w};
#pragma unroll
      for (int i = 0; i < 8; ++i)
#pragma unroll
        for (int j = 0; j < 4; ++j) acc[i][j] += av[i] * bv[j];
    }
  }
#pragma unroll
  for (int i = 0; i < 8; ++i) {
    const int grow = row0 + trow + i;
    if (grow >= NN) continue;
#pragma unroll
    for (int j = 0; j < 4; ++j) {
      const int col = col0 + tcol + j;
      float v = acc[i][j];
      if (col < 900)                    xiou[(size_t)grow*900 + col] = v + b_ioux[col];
      else if (col < 1200 && grow < NI) fxo[(size_t)grow*300 + (col-900)] = v + b_fx[col-900];
    }
  }
}

// ---- iou GEMM tile: ioubuf[r][c] = hsb[start+r]@W_iouh + xiou[start+r] + b_iouh ----
__device__ void gemm_iou_tile(Smem& sm, int row0, int col0, int M, int start,
    const float* __restrict__ hsb, const float* __restrict__ xiou,
    const float* __restrict__ W_iouh, const float* __restrict__ b_iouh,
    float* __restrict__ ioubuf)
{
  const int tid = threadIdx.x;
  float acc[8][4] = {};
  const int trow = (tid >> 4) * 8;
  const int tcol = (tid & 15) * 4;
  const int ar  = tid >> 1;
  const int akh = (tid & 1) * 8;
  const int bk  = tid >> 4;
  const int bc  = (tid & 15) * 4;
  for (int k0 = 0; k0 < 300; k0 += 16) {
    __syncthreads();
    {
      float4 v0 = {0,0,0,0}, v1 = {0,0,0,0};
      const int grow = row0 + ar;
      const int kb = k0 + akh;
      if (grow < M) {
        const float* src = hsb + (size_t)(start + grow) * 300;
        if (kb + 3 < 300) v0 = *(const float4*)(src + kb);
        if (kb + 7 < 300) v1 = *(const float4*)(src + kb + 4);
      }
      sm.g.As[akh+0][ar] = v0.x; sm.g.As[akh+1][ar] = v0.y; sm.g.As[akh+2][ar] = v0.z; sm.g.As[akh+3][ar] = v0.w;
      sm.g.As[akh+4][ar] = v1.x; sm.g.As[akh+5][ar] = v1.y; sm.g.As[akh+6][ar] = v1.z; sm.g.As[akh+7][ar] = v1.w;
    }
    {
      float4 v = {0,0,0,0};
      const int k = k0 + bk;
      const int col = col0 + bc;
      if (k < 300 && col < 900) v = *(const float4*)(W_iouh + (size_t)k * 900 + col);
      *(float4*)&sm.g.Bs[bk][bc] = v;
    }
    __syncthreads();
#pragma unroll
    for (int kk = 0; kk < 16; ++kk) {
      float4 a0 = *(const float4*)&sm.g.As[kk][trow];
      float4 a1 = *(const float4*)&sm.g.As[kk][trow + 4];
      float4 b  = *(const float4*)&sm.g.Bs[kk][tcol];
      float av[8] = {a0.x,a0.y,a0.z,a0.w,a1.x,a1.y,a1.z,a1.w};
      float bv[4] = {b.x,b.y,b.z,b.w};
#pragma unroll
      for (int i = 0; i < 8; ++i)
#pragma unroll
        for (int j = 0; j < 4; ++j) acc[i][j] += av[i] * bv[j];
    }
  }
#pragma unroll
  for (int i = 0; i < 8; ++i) {
    const int grow = row0 + trow + i;
    if (grow >= M) continue;
#pragma unroll
    for (int j = 0; j < 4; ++j) {
      const int col = col0 + tcol + j;
      if (col < 900)
        ioubuf[(size_t)grow*900 + col] = acc[i][j] + xiou[(size_t)(start+grow)*900 + col] + b_iouh[col];
    }
  }
}

// ---- W_fh GEMM tile with fused f-gate + fc reduction (thread's 8 rows = one parent) ----
__device__ void gemm_fcb_tile(Smem& sm, int row0, int col0, int M, int pstart,
    const float* __restrict__ h_cur, const float* __restrict__ c_cur,
    const float* __restrict__ W_fh, const float* __restrict__ b_fh,
    const float* __restrict__ fxo, float* __restrict__ fcb)
{
  const int tid = threadIdx.x;
  float acc[8][4] = {};
  const int trow = (tid >> 4) * 8;
  const int tcol = (tid & 15) * 4;
  const int ar  = tid >> 1;
  const int akh = (tid & 1) * 8;
  const int bk  = tid >> 4;
  const int bc  = (tid & 15) * 4;
  for (int k0 = 0; k0 < 300; k0 += 16) {
    __syncthreads();
    {
      float4 v0 = {0,0,0,0}, v1 = {0,0,0,0};
      const int grow = row0 + ar;
      const int kb = k0 + akh;
      if (grow < M) {
        const float* src = h_cur + (size_t)grow * 300;
        if (kb + 3 < 300) v0 = *(const float4*)(src + kb);
        if (kb + 7 < 300) v1 = *(const float4*)(src + kb + 4);
      }
      sm.g.As[akh+0][ar] = v0.x; sm.g.As[akh+1][ar] = v0.y; sm.g.As[akh+2][ar] = v0.z; sm.g.As[akh+3][ar] = v0.w;
      sm.g.As[akh+4][ar] = v1.x; sm.g.As[akh+5][ar] = v1.y; sm.g.As[akh+6][ar] = v1.z; sm.g.As[akh+7][ar] = v1.w;
    }
    {
      float4 v = {0,0,0,0};
      const int k = k0 + bk;
      const int col = col0 + bc;
      if (k < 300 && col < 300) v = *(const float4*)(W_fh + (size_t)k * 300 + col);
      *(float4*)&sm.g.Bs[bk][bc] = v;
    }
    __syncthreads();
#pragma unroll
    for (int kk = 0; kk < 16; ++kk) {
      float4 a0 = *(const float4*)&sm.g.As[kk][trow];
      float4 a1 = *(const float4*)&sm.g.As[kk][trow + 4];
      float4 b  = *(const float4*)&sm.g.Bs[kk][tcol];
      float av[8] = {a0.x,a0.y,a0.z,a0.w,a1.x,a1.y,a1.z,a1.w};
      float bv[4] = {b.x,b.y,b.z,b.w};
#pragma unroll
      for (int i = 0; i < 8; ++i)
#pragma unroll
        for (int j = 0; j < 4; ++j) acc[i][j] += av[i] * bv[j];
    }
  }
  const int r0 = row0 + trow;
  if (r0 < M) {
    const int p = pstart + (r0 >> 3);
#pragma unroll
    for (int j = 0; j < 4; ++j) {
      const int col = col0 + tcol + j;
      if (col >= 300) continue;
      const float add = b_fh[col] + fxo[(size_t)p*300 + col];
      float fc = 0.f;
#pragma unroll
      for (int i = 0; i < 8; ++i)
        fc += sigm(acc[i][j] + add) * c_cur[(size_t)(r0 + i)*300 + col];
      fcb[(size_t)p*300 + col] = fc;
    }
  }
}

// ---- gates + h-sum for one parent group ----
__device__ void gates_unit(int vb, int pstart, int cstart, int leaf,
    const float* __restrict__ xiou, const float* __restrict__ ioubuf,
    const float* __restrict__ b_iouh, const float* __restrict__ fcb,
    float* __restrict__ h_cur, float* __restrict__ c_cur, float* __restrict__ hsb)
{
  const int p = pstart + vb;
  for (int j = threadIdx.x; j < 300; j += 256) {
    float hsum = 0.f;
#pragma unroll
    for (int k = 0; k < 8; ++k) {
      const int rel = vb * 8 + k;
      float iv, ov, uv;
      if (leaf) {
        const float* x = xiou + (size_t)(cstart + rel) * 900;
        iv = x[j] + b_iouh[j];
        ov = x[300 + j] + b_iouh[300 + j];
        uv = x[600 + j] + b_iouh[600 + j];
      } else {
        const float* x = ioubuf + (size_t)rel * 900;
        iv = x[j]; ov = x[300 + j]; uv = x[600 + j];
      }
      float cc = sigm(iv) * tanhf(uv);
      if (!leaf) cc += fcb[(size_t)(cstart + rel) * 300 + j];
      float hh = sigm(ov) * tanhf(cc);
      c_cur[(size_t)rel * 300 + j] = cc;
      h_cur[(size_t)rel * 300 + j] = hh;
      hsum += hh;
    }
    hsb[(size_t)p * 300 + j] = hsum;
  }
}

// ---- per-node for nodes 1..8 (parent = root); atomics into root accumulators ----
__device__ void node_unit(Smem& sm, int node,
    const float* __restrict__ xiou, const float* __restrict__ fxo,
    const float* __restrict__ W_iouh, const float* __restrict__ b_iouh,
    const float* __restrict__ W_fh, const float* __restrict__ b_fh,
    float* __restrict__ hsb, float* __restrict__ fcb)
{
  const int tid = threadIdx.x;
  __syncthreads();
  for (int j = tid; j < 300; j += 256) sm.n.hs[j] = hsb[(size_t)node*300 + j];
  __syncthreads();
  for (int j = tid; j < 900; j += 256) {
    float acc = xiou[(size_t)node*900 + j] + b_iouh[j];
    for (int k = 0; k < 300; ++k) acc += sm.n.hs[k] * W_iouh[k*900 + j];
    sm.n.siou[j] = acc;
  }
  __syncthreads();
  for (int j = tid; j < 300; j += 256) {
    float cc = sigm(sm.n.siou[j]) * tanhf(sm.n.siou[600 + j]) + fcb[(size_t)node*300 + j];
    sm.n.sc[j] = cc;
    sm.n.sh[j] = sigm(sm.n.siou[300 + j]) * tanhf(cc);
  }
  __syncthreads();
  for (int j = tid; j < 300; j += 256) {
    float acc = b_fh[j] + fxo[j];   // parent is root: fxo row 0
    for (int k = 0; k < 300; ++k) acc += sm.n.sh[k] * W_fh[k*300 + j];
    float f = sigm(acc);
    atomicAdd(&hsb[j], sm.n.sh[j]);
    atomicAdd(&fcb[j], f * sm.n.sc[j]);
  }
}

// ---- root: gates + W_lin head straight to d_out ----
__device__ void root_unit(Smem& sm,
    const float* __restrict__ xiou,
    const float* __restrict__ W_iouh, const float* __restrict__ b_iouh,
    const float* __restrict__ hsb, const float* __restrict__ fcb,
    const float* __restrict__ W_lin, const float* __restrict__ b_lin,
    float* __restrict__ out)
{
  const int tid = threadIdx.x;
  __syncthreads();
  for (int j = tid; j < 300; j += 256) sm.n.hs[j] = hsb[j];
  __syncthreads();
  for (int j = tid; j < 900; j += 256) {
    float acc = xiou[j] + b_iouh[j];
    for (int k = 0; k < 300; ++k) acc += sm.n.hs[k] * W_iouh[k*900 + j];
    sm.n.siou[j] = acc;
  }
  __syncthreads();
  for (int j = tid; j < 300; j += 256) {
    float cc = sigm(sm.n.siou[j]) * tanhf(sm.n.siou[600 + j]) + fcb[j];
    sm.n.sc[j] = cc;
    sm.n.sh[j] = sigm(sm.n.siou[300 + j]) * tanhf(cc);
  }
  __syncthreads();
  for (int j = tid; j < 42; j += 256) {
    float acc = b_lin[j];
    for (int k = 0; k < 300; ++k) acc += sm.n.sc[k] * W_lin[k*42 + j];
    out[j] = acc;
  }
  for (int j = tid; j < 300; j += 256) out[42 + j] = sm.n.sh[j];
}

__global__ __launch_bounds__(256, 4) void mega(
    const int* __restrict__ tokens, const float* __restrict__ embed,
    const float* __restrict__ W_ioux, const float* __restrict__ b_ioux,
    const float* __restrict__ W_iouh, const float* __restrict__ b_iouh,
    const float* __restrict__ W_fx, const float* __restrict__ b_fx,
    const float* __restrict__ W_fh, const float* __restrict__ b_fh,
    const float* __restrict__ W_lin, const float* __restrict__ b_lin,
    float* __restrict__ out,
    float* xiou, float* fxo, float* hsb, float* fcb,
    float* h_cur, float* c_cur, float* ioubuf, unsigned* bar)
{
  __shared__ Smem sm;
  const int bid = blockIdx.x;

  // P0: X GEMM — 703 tiles over 512 blocks
  for (int t = bid; t < 703; t += GRID) {
    const int ty = t / 19, tx = t % 19;
    const int row0 = ty * 128, col0 = tx * 64;
    if (!(col0 >= 960 && row0 >= 640))
      gemm_x_tile(sm, row0, col0, tokens, embed, W_ioux, W_fx, b_ioux, b_fx, xiou, fxo);
  }
  gsync(bar, 0);
  // P1: leaf gates (parents 73..584)
  gates_unit(bid, 73, 585, 1, xiou, nullptr, b_iouh, nullptr, h_cur, c_cur, hsb);
  gsync(bar, 1);
  // P2: fcb leaf (M=4096 -> 32x5 tiles)
  if (bid < 160) gemm_fcb_tile(sm, (bid/5)*128, (bid%5)*64, 4096, 73, h_cur, c_cur, W_fh, b_fh, fxo, fcb);
  gsync(bar, 2);
  // P3: iou 512 (4x15 tiles)
  if (bid < 60) gemm_iou_tile(sm, (bid/15)*128, (bid%15)*64, 512, 73, hsb, xiou, W_iouh, b_iouh, ioubuf);
  gsync(bar, 3);
  // P4: gates 512 (parents 9..72)
  if (bid < 64) gates_unit(bid, 9, 73, 0, nullptr, ioubuf, b_iouh, fcb, h_cur, c_cur, hsb);
  gsync(bar, 4);
  // P5: fcb 512 (4x5 tiles)
  if (bid < 20) gemm_fcb_tile(sm, (bid/5)*128, (bid%5)*64, 512, 9, h_cur, c_cur, W_fh, b_fh, fxo, fcb);
  gsync(bar, 5);
  // P6: iou 64 (1x15 tiles)
  if (bid < 15) gemm_iou_tile(sm, 0, bid*64, 64, 9, hsb, xiou, W_iouh, b_iouh, ioubuf);
  gsync(bar, 6);
  // P7: gates 64 (parents 1..8)
  if (bid < 8) gates_unit(bid, 1, 9, 0, nullptr, ioubuf, b_iouh, fcb, h_cur, c_cur, hsb);
  gsync(bar, 7);
  // P8: fcb 64 (1x5 tiles)
  if (bid < 5) gemm_fcb_tile(sm, 0, bid*64, 64, 1, h_cur, c_cur, W_fh, b_fh, fxo, fcb);
  gsync(bar, 8);
  // P9: nodes 1..8
  if (bid < 8) node_unit(sm, 1 + bid, xiou, fxo, W_iouh, b_iouh, W_fh, b_fh, hsb, fcb);
  gsync(bar, 9);
  // P10: root
  if (bid == 0) root_unit(sm, xiou, W_iouh, b_iouh, hsb, fcb, W_lin, b_lin, out);
}

extern "C" void kernel_launch(void* const* d_in, const int* in_sizes, int n_in,
                              void* d_out, int out_size, void* d_ws, size_t ws_size,
                              hipStream_t stream) {
  const int* tokens   = (const int*)d_in[0];
  const float* embed  = (const float*)d_in[3];
  const float* W_ioux = (const float*)d_in[4];
  const float* b_ioux = (const float*)d_in[5];
  const float* W_iouh = (const float*)d_in[6];
  const float* b_iouh = (const float*)d_in[7];
  const float* W_fx   = (const float*)d_in[8];
  const float* b_fx   = (const float*)d_in[9];
  const float* W_fh   = (const float*)d_in[10];
  const float* b_fh   = (const float*)d_in[11];
  const float* W_lin  = (const float*)d_in[12];
  const float* b_lin  = (const float*)d_in[13];
  float* out = (float*)d_out;

  float* ws     = (float*)d_ws;
  float* xiou   = ws;                                  // NN*900
  float* fxo    = xiou   + (size_t)NN * 900;           // NI*300
  float* hsb    = fxo    + (size_t)NI * 300;           // NI*300
  float* fcb    = hsb    + (size_t)NI * 300;           // NI*300
  float* h_cur  = fcb    + (size_t)NI * 300;           // 4096*300
  float* c_cur  = h_cur  + (size_t)4096 * 300;         // 4096*300
  float* ioubuf = c_cur  + (size_t)4096 * 300;         // 512*900
  unsigned* bar = (unsigned*)(ioubuf + (size_t)512 * 900);  // 16 counters

  hipMemsetAsync(bar, 0, 16 * sizeof(unsigned), stream);
  hipMemsetAsync(hsb, 0, 300 * sizeof(float), stream);   // root accumulators
  hipMemsetAsync(fcb, 0, 300 * sizeof(float), stream);

  mega<<<GRID, 256, 0, stream>>>(tokens, embed, W_ioux, b_ioux, W_iouh, b_iouh,
      W_fx, b_fx, W_fh, b_fh, W_lin, b_lin, out,
      xiou, fxo, hsb, fcb, h_cur, c_cur, ioubuf, bar);
}